// Round 7
// baseline (308.386 us; speedup 1.0000x reference)
//
#include <hip/hip_runtime.h>
#include <hip/hip_bf16.h>

#define INFEAT 4096
#define OUTFEAT 11008
#define TOKENS 2048

typedef int v4i __attribute__((ext_vector_type(4)));
typedef __bf16 bf16_t;
typedef bf16_t bf16x4 __attribute__((ext_vector_type(4)));
typedef bf16_t bf16x8 __attribute__((ext_vector_type(8)));
typedef float f32x4 __attribute__((ext_vector_type(4)));

__device__ __forceinline__ void async_copy16(const void* g, void* l) {
    __builtin_amdgcn_global_load_lds((const __attribute__((address_space(1))) void*)g,
                                     (__attribute__((address_space(3))) void*)l,
                                     16, 0, 0);
}

// ---- fused pre-pass (verified R1/R6): blocks [0,2752) transpose weights
// ---- (16B/lane loads), blocks [2752,4800) per-token i8 quantization of x.
__global__ __launch_bounds__(256) void prep(
    const float* __restrict__ x, const unsigned int* __restrict__ qw,
    unsigned int* __restrict__ xq, float* __restrict__ xscale, int* __restrict__ xsum,
    unsigned char* __restrict__ wt)
{
    __shared__ unsigned int Tw[64 * 64];   // 16 KB transpose staging
    __shared__ float smax[4];
    __shared__ int ssum[4];
    const int tid = threadIdx.x;

    if (blockIdx.x < 2752) {
        // ---------------- weight transpose: qw[kp][n] -> wt[n][k] bytes (^0x80)
        const int bid = blockIdx.x;
        const int n0  = (bid % 172) * 64;
        const int kp0 = (bid / 172) * 64;
        const int tn4 = tid & 15;          // uint4 index along n
        const int kb  = tid >> 4;          // 0..15
        #pragma unroll
        for (int it = 0; it < 4; ++it) {
            const int kp = kb + it * 16;   // 0..63, kp>>2 wave-uniform
            uint4 q = *(const uint4*)&qw[(size_t)(kp0 + kp) * OUTFEAT + n0 + tn4 * 4];
            q.x ^= 0x80808080u; q.y ^= 0x80808080u; q.z ^= 0x80808080u; q.w ^= 0x80808080u;
            const int ks = kp >> 2, kq = kp & 3;
            const int n = tn4 * 4;
            Tw[(n + 0) * 64 + ((ks ^ ((n + 0) & 15)) << 2) + kq] = q.x;
            Tw[(n + 1) * 64 + ((ks ^ ((n + 1) & 15)) << 2) + kq] = q.y;
            Tw[(n + 2) * 64 + ((ks ^ ((n + 2) & 15)) << 2) + kq] = q.z;
            Tw[(n + 3) * 64 + ((ks ^ ((n + 3) & 15)) << 2) + kq] = q.w;
        }
        __syncthreads();
        #pragma unroll
        for (int i = 0; i < 4; ++i) {
            const int flat = i * 256 + tid;
            const int n = flat >> 4;       // 0..63
            const int c = flat & 15;       // 16B chunk within 256B row
            uint4 v = *(const uint4*)&Tw[n * 64 + ((c ^ (n & 15)) * 4)];
            *(uint4*)&wt[(size_t)(n0 + n) * INFEAT + (size_t)kp0 * 4 + c * 16] = v;
        }
    } else {
        // ---------------- per-token i8 quantization (verified round-0)
        const int row = blockIdx.x - 2752;
        const int lane = tid & 63, wid = tid >> 6;
        const float* xr = x + (size_t)row * INFEAT;

        float4 v[4];
        #pragma unroll
        for (int i = 0; i < 4; ++i) v[i] = *(const float4*)&xr[tid * 16 + i * 4];

        float am = 0.f;
        #pragma unroll
        for (int i = 0; i < 4; ++i)
            am = fmaxf(am, fmaxf(fmaxf(fabsf(v[i].x), fabsf(v[i].y)),
                                 fmaxf(fabsf(v[i].z), fabsf(v[i].w))));
        #pragma unroll
        for (int o = 32; o > 0; o >>= 1) am = fmaxf(am, __shfl_xor(am, o, 64));
        if (lane == 0) smax[wid] = am;
        __syncthreads();
        am = fmaxf(fmaxf(smax[0], smax[1]), fmaxf(smax[2], smax[3]));
        const float inv = am > 0.f ? 127.0f / am : 0.f;
        const float sc  = am > 0.f ? am / 127.0f : 0.f;

        int lsum = 0;
        unsigned int pk[4];
        #pragma unroll
        for (int i = 0; i < 4; ++i) {
            int q0 = (int)rintf(fminf(fmaxf(v[i].x * inv, -127.f), 127.f));
            int q1 = (int)rintf(fminf(fmaxf(v[i].y * inv, -127.f), 127.f));
            int q2 = (int)rintf(fminf(fmaxf(v[i].z * inv, -127.f), 127.f));
            int q3 = (int)rintf(fminf(fmaxf(v[i].w * inv, -127.f), 127.f));
            lsum += q0 + q1 + q2 + q3;
            pk[i] = (q0 & 255) | ((q1 & 255) << 8) | ((q2 & 255) << 16) | ((unsigned)(q3 & 255) << 24);
        }
        *(uint4*)&xq[(size_t)row * (INFEAT / 4) + tid * 4] = *(uint4*)pk;

        #pragma unroll
        for (int o = 32; o > 0; o >>= 1) lsum += __shfl_xor(lsum, o, 64);
        if (lane == 0) ssum[wid] = lsum;
        __syncthreads();
        if (tid == 0) {
            xsum[row] = ssum[0] + ssum[1] + ssum[2] + ssum[3];
            xscale[row] = sc;
        }
    }
}

// ---- main GEMM: counted-vmcnt pipeline (verified R5) at BK=64:
// ---- LDS/block 32 KB -> 4 blocks/CU (R0's proven TLP) + depth-2 prefetch +
// ---- counted vmcnt(4). Block mapping reverted to R0/R5 (accidental A-panel
// ---- L2 residency beats the R6 swizzle; R6 A/B showed swizzle -8%).
// ---- Row stride 64 B: swizzle g(r)=(r+(r>>2))&3, slot = chunk ^ g(r) ->
// ---- each 8-lane b128 group hits all 32 banks once (checked by hand).
// ---- vmcnt ledger: prologue 8 out -> vmcnt(4) retires S(0). Iter t: +4
// ---- (S(t+2)), vmcnt(4) retires S(t+1). Tail t>=NT-2: vmcnt(0).
__global__ __launch_bounds__(256, 4) void q3gemm_i8e(
    const unsigned char* __restrict__ xqb, const unsigned char* __restrict__ wt,
    const float* __restrict__ scales, const int* __restrict__ zeros,
    const float* __restrict__ bias, const float* __restrict__ xscale,
    const int* __restrict__ xsum, float* __restrict__ out)
{
    __shared__ unsigned char Als[2][128 * 64];   // 8 KB each: [m][k] bytes
    __shared__ unsigned char Bls[2][128 * 64];   // 8 KB each: [n][k] bytes

    const int tid = threadIdx.x;
    // n-panel grouping: 16 consecutive blocks share one weight panel
    const int n0 = (blockIdx.x >> 4) * 128;
    const int m0 = (blockIdx.x & 15) * 128;

    const int wid = tid >> 6, lane = tid & 63;
    const int wm = (wid & 1) * 64, wn = (wid >> 1) * 64;
    const int lr = lane & 15, lq = lane >> 4;

    // staging decomposition: wave stages rows wid*32 .. wid*32+31 (2 groups of 16)
    const int rb0 = wid * 32;
    const int rs  = lane >> 2;       // 0..15 row within group
    const int sl  = lane & 3;        // destination chunk slot (16B units)

    v4i acc[4][4];
    #pragma unroll
    for (int i = 0; i < 4; ++i)
        #pragma unroll
        for (int j = 0; j < 4; ++j)
            acc[i][j] = (v4i){0, 0, 0, 0};

    // 4 global_load_lds per thread per K-tile (A:2, B:2), source pre-swizzled
#define STAGE(T, C) do {                                                              \
    const int kk0_ = (T) * 64;                                                        \
    _Pragma("unroll")                                                                 \
    for (int p_ = 0; p_ < 2; ++p_) {                                                  \
        const int r_ = rb0 + p_ * 16 + rs;                                            \
        const int s_ = sl ^ ((r_ + (r_ >> 2)) & 3);                                   \
        async_copy16(&xqb[(size_t)(m0 + r_) * INFEAT + kk0_ + s_ * 16],               \
                     &Als[C][(rb0 + p_ * 16) * 64]);                                  \
    }                                                                                 \
    _Pragma("unroll")                                                                 \
    for (int p_ = 0; p_ < 2; ++p_) {                                                  \
        const int r_ = rb0 + p_ * 16 + rs;                                            \
        const int s_ = sl ^ ((r_ + (r_ >> 2)) & 3);                                   \
        async_copy16(&wt[(size_t)(n0 + r_) * INFEAT + kk0_ + s_ * 16],                \
                     &Bls[C][(rb0 + p_ * 16) * 64]);                                  \
    }                                                                                 \
} while (0)

    const int NT = INFEAT / 64;   // 64

    // prologue: stage tiles 0 and 1; wait for tile 0 (4 newest may fly)
    STAGE(0, 0);
    STAGE(1, 1);
    asm volatile("s_waitcnt vmcnt(4)" ::: "memory");
    __builtin_amdgcn_sched_barrier(0);
    __builtin_amdgcn_s_barrier();
    __builtin_amdgcn_sched_barrier(0);

    for (int t = 0; t < NT; ++t) {
        const int cur = t & 1;
        const unsigned char* Ab = Als[cur];
        const unsigned char* Bb = Bls[cur];

        // ---- 8 fragments of this K-tile -> regs (lane holds k = lq*16..+15)
        v4i af[4], bfv[4];
        #pragma unroll
        for (int q = 0; q < 4; ++q) {
            const int ra = wm + q * 16 + lr;
            const int pa = lq ^ ((ra + (ra >> 2)) & 3);
            af[q] = *(const v4i*)&Ab[ra * 64 + pa * 16];
            const int rb = wn + q * 16 + lr;
            const int pb = lq ^ ((rb + (rb >> 2)) & 3);
            bfv[q] = *(const v4i*)&Bb[rb * 64 + pb * 16];
        }
        asm volatile("s_waitcnt lgkmcnt(0)" ::: "memory");   // frags in regs
        __builtin_amdgcn_sched_barrier(0);
        __builtin_amdgcn_s_barrier();                        // all waves done reading buf[cur]
        __builtin_amdgcn_sched_barrier(0);                   // pin: no stage above this line

        // ---- issue prefetch of tile t+2 into the just-freed buffer
        if (t + 2 < NT) STAGE(t + 2, cur);

        // ---- MFMA x16 (stage loads fly underneath)
        #pragma unroll
        for (int i = 0; i < 4; ++i)
            #pragma unroll
            for (int j = 0; j < 4; ++j)
                acc[i][j] = __builtin_amdgcn_mfma_i32_16x16x64_i8(af[i], bfv[j], acc[i][j], 0, 0, 0);

        // ---- counted wait: tile t+1 (4 oldest) landed; t+2's 4 may fly
        __builtin_amdgcn_sched_barrier(0);
        if (t < NT - 2) { asm volatile("s_waitcnt vmcnt(4)" ::: "memory"); }
        else            { asm volatile("s_waitcnt vmcnt(0)" ::: "memory"); }
        __builtin_amdgcn_sched_barrier(0);
        __builtin_amdgcn_s_barrier();
        __builtin_amdgcn_sched_barrier(0);
    }
#undef STAGE

    // epilogue: out = sx[m]*s[n]*(acc + (128-z[n])*xsum[m]) + bias[n]  (verified)
    #pragma unroll
    for (int j = 0; j < 4; ++j) {
        const int col = n0 + wn + j * 16 + lr;
        const float sn = scales[col];
        const int zi = 128 - zeros[col];
        const float bv = bias[col];
        #pragma unroll
        for (int i = 0; i < 4; ++i) {
            const int rb = m0 + wm + i * 16 + lq * 4;
            #pragma unroll
            for (int r = 0; r < 4; ++r) {
                const int tot = acc[i][j][r] + zi * xsum[rb + r];
                out[(size_t)(rb + r) * OUTFEAT + col] = xscale[rb + r] * sn * (float)tot + bv;
            }
        }
    }
}

// ---------------- fallback (round-1 fused kernel, used if ws too small) ----
#define LDSS 72
__global__ __launch_bounds__(256) void q3gemm_fb(
    const float* __restrict__ x, const unsigned int* __restrict__ qw,
    const float* __restrict__ scales, const int* __restrict__ zeros,
    const float* __restrict__ bias, float* __restrict__ out)
{
    __shared__ bf16_t Als[128 * LDSS];
    __shared__ bf16_t Bls[128 * LDSS];
    const int tid = threadIdx.x;
    const int m0 = blockIdx.y * 128;
    const int n0 = blockIdx.x * 128;
    const int bcol = tid & 127;
    const int bpr  = tid >> 7;
    const float scf = scales[n0 + bcol];
    const float nzs = (float)zeros[n0 + bcol] * scf;
    const int acolg = tid & 15;
    const int arow0 = tid >> 4;
    const int wid  = tid >> 6;
    const int lane = tid & 63;
    const int wm = (wid & 1) * 64;
    const int wn = (wid >> 1) * 64;
    const int lr = lane & 15;
    const int lq = lane >> 4;
    f32x4 acc[4][4];
    #pragma unroll
    for (int i = 0; i < 4; ++i)
        #pragma unroll
        for (int j = 0; j < 4; ++j) acc[i][j] = (f32x4)0.0f;
    for (int kt = 0; kt < INFEAT / 64; ++kt) {
        const int k0 = kt * 64;
        #pragma unroll
        for (int p = 0; p < 8; ++p) {
            const int row = arow0 + p * 16;
            const float4 v = *(const float4*)&x[(size_t)(m0 + row) * INFEAT + k0 + acolg * 4];
            bf16x4 b;
            b[0] = (bf16_t)v.x; b[1] = (bf16_t)v.y; b[2] = (bf16_t)v.z; b[3] = (bf16_t)v.w;
            *(bf16x4*)&Als[row * LDSS + acolg * 4] = b;
        }
        const int kp0 = k0 >> 2;
        #pragma unroll
        for (int it = 0; it < 8; ++it) {
            const int prel = it * 2 + bpr;
            const unsigned int q = qw[(size_t)(kp0 + prel) * OUTFEAT + n0 + bcol];
            bf16x4 b;
            b[0] = (bf16_t)((float)(q & 0xFFu)        * scf - nzs);
            b[1] = (bf16_t)((float)((q >> 8) & 0xFFu) * scf - nzs);
            b[2] = (bf16_t)((float)((q >> 16) & 0xFFu)* scf - nzs);
            b[3] = (bf16_t)((float)(q >> 24)          * scf - nzs);
            *(bf16x4*)&Bls[bcol * LDSS + prel * 4] = b;
        }
        __syncthreads();
        #pragma unroll
        for (int ks = 0; ks < 2; ++ks) {
            bf16x8 af[4], bfv[4];
            #pragma unroll
            for (int t = 0; t < 4; ++t) {
                af[t]  = *(const bf16x8*)&Als[(wm + t * 16 + lr) * LDSS + ks * 32 + lq * 8];
                bfv[t] = *(const bf16x8*)&Bls[(wn + t * 16 + lr) * LDSS + ks * 32 + lq * 8];
            }
            #pragma unroll
            for (int i = 0; i < 4; ++i)
                #pragma unroll
                for (int j = 0; j < 4; ++j)
                    acc[i][j] = __builtin_amdgcn_mfma_f32_16x16x32_bf16(af[i], bfv[j], acc[i][j], 0, 0, 0);
        }
        __syncthreads();
    }
    #pragma unroll
    for (int j = 0; j < 4; ++j) {
        const int col = n0 + wn + j * 16 + lr;
        const float bv = bias[col];
        #pragma unroll
        for (int i = 0; i < 4; ++i) {
            const int rbs = m0 + wm + i * 16 + lq * 4;
            #pragma unroll
            for (int r = 0; r < 4; ++r)
                out[(size_t)(rbs + r) * OUTFEAT + col] = acc[i][j][r] + bv;
        }
    }
}

extern "C" void kernel_launch(void* const* d_in, const int* in_sizes, int n_in,
                              void* d_out, int out_size, void* d_ws, size_t ws_size,
                              hipStream_t stream) {
    const float*        x      = (const float*)d_in[0];
    const unsigned int* qw     = (const unsigned int*)d_in[1];
    const float*        scales = (const float*)d_in[2];
    const int*          zeros  = (const int*)d_in[3];
    const float*        bias   = (const float*)d_in[4];
    float*              out    = (float*)d_out;

    const size_t wt_bytes = (size_t)OUTFEAT * INFEAT;        // 45.1 MB i8 transposed weights
    const size_t xq_bytes = (size_t)TOKENS * INFEAT;         // 8.4 MB packed i8 x
    const size_t need = wt_bytes + xq_bytes + TOKENS * (sizeof(float) + sizeof(int)) + 256;

    if (ws_size >= need) {
        unsigned char* wt = (unsigned char*)d_ws;
        unsigned int* xq  = (unsigned int*)((char*)d_ws + wt_bytes);
        float* xscale = (float*)((char*)d_ws + wt_bytes + xq_bytes);
        int*   xsum   = (int*)((char*)d_ws + wt_bytes + xq_bytes + TOKENS * sizeof(float));

        prep<<<dim3(2752 + TOKENS), dim3(256), 0, stream>>>(x, qw, xq, xscale, xsum, wt);
        q3gemm_i8e<<<dim3((OUTFEAT / 128) * (TOKENS / 128)), dim3(256), 0, stream>>>(
            (const unsigned char*)xq, wt, scales, zeros, bias, xscale, xsum, out);
    } else {
        q3gemm_fb<<<dim3(OUTFEAT / 128, TOKENS / 128), dim3(256), 0, stream>>>(
            x, qw, scales, zeros, bias, out);
    }
}

// Round 10
// 263.498 us; speedup vs baseline: 1.1704x; 1.1704x over previous
//
#include <hip/hip_runtime.h>
#include <hip/hip_bf16.h>

#define INFEAT 4096
#define OUTFEAT 11008
#define TOKENS 2048

typedef int v4i __attribute__((ext_vector_type(4)));
typedef __bf16 bf16_t;
typedef bf16_t bf16x4 __attribute__((ext_vector_type(4)));
typedef bf16_t bf16x8 __attribute__((ext_vector_type(8)));
typedef float f32x4 __attribute__((ext_vector_type(4)));

__device__ __forceinline__ void async_copy16(const void* g, void* l) {
    __builtin_amdgcn_global_load_lds((const __attribute__((address_space(1))) void*)g,
                                     (__attribute__((address_space(3))) void*)l,
                                     16, 0, 0);
}

// ---- fused pre-pass (verified R1/R6): blocks [0,2752) transpose weights
// ---- (16B/lane loads), blocks [2752,4800) per-token i8 quantization of x.
__global__ __launch_bounds__(256) void prep(
    const float* __restrict__ x, const unsigned int* __restrict__ qw,
    unsigned int* __restrict__ xq, float* __restrict__ xscale, int* __restrict__ xsum,
    unsigned char* __restrict__ wt)
{
    __shared__ unsigned int Tw[64 * 64];   // 16 KB transpose staging
    __shared__ float smax[4];
    __shared__ int ssum[4];
    const int tid = threadIdx.x;

    if (blockIdx.x < 2752) {
        // ---------------- weight transpose: qw[kp][n] -> wt[n][k] bytes (^0x80)
        const int bid = blockIdx.x;
        const int n0  = (bid % 172) * 64;
        const int kp0 = (bid / 172) * 64;
        const int tn4 = tid & 15;          // uint4 index along n
        const int kb  = tid >> 4;          // 0..15
        #pragma unroll
        for (int it = 0; it < 4; ++it) {
            const int kp = kb + it * 16;   // 0..63, kp>>2 wave-uniform
            uint4 q = *(const uint4*)&qw[(size_t)(kp0 + kp) * OUTFEAT + n0 + tn4 * 4];
            q.x ^= 0x80808080u; q.y ^= 0x80808080u; q.z ^= 0x80808080u; q.w ^= 0x80808080u;
            const int ks = kp >> 2, kq = kp & 3;
            const int n = tn4 * 4;
            Tw[(n + 0) * 64 + ((ks ^ ((n + 0) & 15)) << 2) + kq] = q.x;
            Tw[(n + 1) * 64 + ((ks ^ ((n + 1) & 15)) << 2) + kq] = q.y;
            Tw[(n + 2) * 64 + ((ks ^ ((n + 2) & 15)) << 2) + kq] = q.z;
            Tw[(n + 3) * 64 + ((ks ^ ((n + 3) & 15)) << 2) + kq] = q.w;
        }
        __syncthreads();
        #pragma unroll
        for (int i = 0; i < 4; ++i) {
            const int flat = i * 256 + tid;
            const int n = flat >> 4;       // 0..63
            const int c = flat & 15;       // 16B chunk within 256B row
            uint4 v = *(const uint4*)&Tw[n * 64 + ((c ^ (n & 15)) * 4)];
            *(uint4*)&wt[(size_t)(n0 + n) * INFEAT + (size_t)kp0 * 4 + c * 16] = v;
        }
    } else {
        // ---------------- per-token i8 quantization (verified round-0)
        const int row = blockIdx.x - 2752;
        const int lane = tid & 63, wid = tid >> 6;
        const float* xr = x + (size_t)row * INFEAT;

        float4 v[4];
        #pragma unroll
        for (int i = 0; i < 4; ++i) v[i] = *(const float4*)&xr[tid * 16 + i * 4];

        float am = 0.f;
        #pragma unroll
        for (int i = 0; i < 4; ++i)
            am = fmaxf(am, fmaxf(fmaxf(fabsf(v[i].x), fabsf(v[i].y)),
                                 fmaxf(fabsf(v[i].z), fabsf(v[i].w))));
        #pragma unroll
        for (int o = 32; o > 0; o >>= 1) am = fmaxf(am, __shfl_xor(am, o, 64));
        if (lane == 0) smax[wid] = am;
        __syncthreads();
        am = fmaxf(fmaxf(smax[0], smax[1]), fmaxf(smax[2], smax[3]));
        const float inv = am > 0.f ? 127.0f / am : 0.f;
        const float sc  = am > 0.f ? am / 127.0f : 0.f;

        int lsum = 0;
        unsigned int pk[4];
        #pragma unroll
        for (int i = 0; i < 4; ++i) {
            int q0 = (int)rintf(fminf(fmaxf(v[i].x * inv, -127.f), 127.f));
            int q1 = (int)rintf(fminf(fmaxf(v[i].y * inv, -127.f), 127.f));
            int q2 = (int)rintf(fminf(fmaxf(v[i].z * inv, -127.f), 127.f));
            int q3 = (int)rintf(fminf(fmaxf(v[i].w * inv, -127.f), 127.f));
            lsum += q0 + q1 + q2 + q3;
            pk[i] = (q0 & 255) | ((q1 & 255) << 8) | ((q2 & 255) << 16) | ((unsigned)(q3 & 255) << 24);
        }
        *(uint4*)&xq[(size_t)row * (INFEAT / 4) + tid * 4] = *(uint4*)pk;

        #pragma unroll
        for (int o = 32; o > 0; o >>= 1) lsum += __shfl_xor(lsum, o, 64);
        if (lane == 0) ssum[wid] = lsum;
        __syncthreads();
        if (tid == 0) {
            xsum[row] = ssum[0] + ssum[1] + ssum[2] + ssum[3];
            xscale[row] = sc;
        }
    }
}

// ---- main GEMM: verified R5 kernel, byte-identical (128x128 tile, 256 thr,
// ---- dbuf 64 KB, 2 blk/CU, depth-2 prefetch, counted vmcnt(8), 16x16x64 i8).
// ---- Measured R5: 110 µs, MfmaUtil 37%, bank conflicts 0.
// ---- vmcnt ledger: prologue 16 out -> vmcnt(8) retires S(0). Iter t: +8
// ---- (S(t+2)), vmcnt(8) retires S(t+1). Tail t>=NT-2: vmcnt(0).
__global__ __launch_bounds__(256, 2) void q3gemm_i8d(
    const unsigned char* __restrict__ xqb, const unsigned char* __restrict__ wt,
    const float* __restrict__ scales, const int* __restrict__ zeros,
    const float* __restrict__ bias, const float* __restrict__ xscale,
    const int* __restrict__ xsum, float* __restrict__ out)
{
    __shared__ unsigned char Als[2][128 * 128];   // 32 KB: [m][k] bytes, chunk c at slot c^(m&7)
    __shared__ unsigned char Bls[2][128 * 128];   // 32 KB: [n][k] bytes, same swizzle

    const int tid = threadIdx.x;
    // n-panel grouping: 16 consecutive blocks share one weight panel
    const int n0 = (blockIdx.x >> 4) * 128;
    const int m0 = (blockIdx.x & 15) * 128;

    const int wid = tid >> 6, lane = tid & 63;
    const int wm = (wid & 1) * 64, wn = (wid >> 1) * 64;
    const int lr = lane & 15, lq = lane >> 4;

    // DMA decomposition: wave stages rows wid*32 .. wid*32+31 (4 groups of 8 rows)
    const int rb0  = wid * 32;
    const int rsub = lane >> 3;      // 0..7
    const int sl   = lane & 7;       // destination chunk slot

    v4i acc[4][4];
    #pragma unroll
    for (int i = 0; i < 4; ++i)
        #pragma unroll
        for (int j = 0; j < 4; ++j)
            acc[i][j] = (v4i){0, 0, 0, 0};

    // 8 global_load_lds per thread per K-tile (A:4, B:4), source pre-swizzled
#define STAGE(T, C) do {                                                              \
    const int kk0_ = (T) * 128;                                                       \
    _Pragma("unroll")                                                                 \
    for (int p_ = 0; p_ < 4; ++p_) {                                                  \
        const int r_ = rb0 + p_ * 8 + rsub;                                           \
        const int s_ = sl ^ (r_ & 7);                                                 \
        async_copy16(&xqb[(size_t)(m0 + r_) * INFEAT + kk0_ + s_ * 16],               \
                     &Als[C][(rb0 + p_ * 8) * 128]);                                  \
    }                                                                                 \
    _Pragma("unroll")                                                                 \
    for (int p_ = 0; p_ < 4; ++p_) {                                                  \
        const int r_ = rb0 + p_ * 8 + rsub;                                           \
        const int s_ = sl ^ (r_ & 7);                                                 \
        async_copy16(&wt[(size_t)(n0 + r_) * INFEAT + kk0_ + s_ * 16],                \
                     &Bls[C][(rb0 + p_ * 8) * 128]);                                  \
    }                                                                                 \
} while (0)

    const int NT = INFEAT / 128;   // 32

    // prologue: stage tiles 0 and 1; wait for tile 0 (8 newest may fly)
    STAGE(0, 0);
    STAGE(1, 1);
    asm volatile("s_waitcnt vmcnt(8)" ::: "memory");
    __builtin_amdgcn_sched_barrier(0);
    __builtin_amdgcn_s_barrier();
    __builtin_amdgcn_sched_barrier(0);

    for (int t = 0; t < NT; ++t) {
        const int cur = t & 1;
        const unsigned char* Ab = Als[cur];
        const unsigned char* Bb = Bls[cur];

        // ---- all 16 fragments of this K-tile -> regs
        v4i af[2][4], bfv[2][4];
        #pragma unroll
        for (int ks = 0; ks < 2; ++ks)
            #pragma unroll
            for (int q = 0; q < 4; ++q) {
                const int ra = wm + q * 16 + lr;
                const int pa = (ks * 4 + lq) ^ (ra & 7);
                af[ks][q] = *(const v4i*)&Ab[ra * 128 + pa * 16];
                const int rb = wn + q * 16 + lr;
                const int pb = (ks * 4 + lq) ^ (rb & 7);
                bfv[ks][q] = *(const v4i*)&Bb[rb * 128 + pb * 16];
            }
        asm volatile("s_waitcnt lgkmcnt(0)" ::: "memory");   // frags in regs
        __builtin_amdgcn_sched_barrier(0);
        __builtin_amdgcn_s_barrier();                        // all waves done reading buf[cur]
        __builtin_amdgcn_sched_barrier(0);                   // pin: no stage above this line

        // ---- issue prefetch of tile t+2 into the just-freed buffer
        if (t + 2 < NT) STAGE(t + 2, cur);

        // ---- MFMA x32 (stage loads fly underneath)
        #pragma unroll
        for (int ks = 0; ks < 2; ++ks)
            #pragma unroll
            for (int i = 0; i < 4; ++i)
                #pragma unroll
                for (int j = 0; j < 4; ++j)
                    acc[i][j] = __builtin_amdgcn_mfma_i32_16x16x64_i8(af[ks][i], bfv[ks][j], acc[i][j], 0, 0, 0);

        // ---- counted wait: tile t+1 (previous stage, 8 oldest) must have landed;
        // ---- tile t+2's 8 loads may remain in flight. Tail drains fully.
        __builtin_amdgcn_sched_barrier(0);
        if (t < NT - 2) { asm volatile("s_waitcnt vmcnt(8)" ::: "memory"); }
        else            { asm volatile("s_waitcnt vmcnt(0)" ::: "memory"); }
        __builtin_amdgcn_sched_barrier(0);
        __builtin_amdgcn_s_barrier();
        __builtin_amdgcn_sched_barrier(0);
    }
#undef STAGE

    // epilogue: out = sx[m]*s[n]*(acc + (128-z[n])*xsum[m]) + bias[n]  (verified)
    #pragma unroll
    for (int j = 0; j < 4; ++j) {
        const int col = n0 + wn + j * 16 + lr;
        const float sn = scales[col];
        const int zi = 128 - zeros[col];
        const float bv = bias[col];
        #pragma unroll
        for (int i = 0; i < 4; ++i) {
            const int rb = m0 + wm + i * 16 + lq * 4;
            #pragma unroll
            for (int r = 0; r < 4; ++r) {
                const int tot = acc[i][j][r] + zi * xsum[rb + r];
                out[(size_t)(rb + r) * OUTFEAT + col] = xscale[rb + r] * sn * (float)tot + bv;
            }
        }
    }
}

// ---------------- fallback (round-1 fused kernel, used if ws too small) ----
#define LDSS 72
__global__ __launch_bounds__(256) void q3gemm_fb(
    const float* __restrict__ x, const unsigned int* __restrict__ qw,
    const float* __restrict__ scales, const int* __restrict__ zeros,
    const float* __restrict__ bias, float* __restrict__ out)
{
    __shared__ bf16_t Als[128 * LDSS];
    __shared__ bf16_t Bls[128 * LDSS];
    const int tid = threadIdx.x;
    const int m0 = blockIdx.y * 128;
    const int n0 = blockIdx.x * 128;
    const int bcol = tid & 127;
    const int bpr  = tid >> 7;
    const float scf = scales[n0 + bcol];
    const float nzs = (float)zeros[n0 + bcol] * scf;
    const int acolg = tid & 15;
    const int arow0 = tid >> 4;
    const int wid  = tid >> 6;
    const int lane = tid & 63;
    const int wm = (wid & 1) * 64;
    const int wn = (wid >> 1) * 64;
    const int lr = lane & 15;
    const int lq = lane >> 4;
    f32x4 acc[4][4];
    #pragma unroll
    for (int i = 0; i < 4; ++i)
        #pragma unroll
        for (int j = 0; j < 4; ++j) acc[i][j] = (f32x4)0.0f;
    for (int kt = 0; kt < INFEAT / 64; ++kt) {
        const int k0 = kt * 64;
        #pragma unroll
        for (int p = 0; p < 8; ++p) {
            const int row = arow0 + p * 16;
            const float4 v = *(const float4*)&x[(size_t)(m0 + row) * INFEAT + k0 + acolg * 4];
            bf16x4 b;
            b[0] = (bf16_t)v.x; b[1] = (bf16_t)v.y; b[2] = (bf16_t)v.z; b[3] = (bf16_t)v.w;
            *(bf16x4*)&Als[row * LDSS + acolg * 4] = b;
        }
        const int kp0 = k0 >> 2;
        #pragma unroll
        for (int it = 0; it < 8; ++it) {
            const int prel = it * 2 + bpr;
            const unsigned int q = qw[(size_t)(kp0 + prel) * OUTFEAT + n0 + bcol];
            bf16x4 b;
            b[0] = (bf16_t)((float)(q & 0xFFu)        * scf - nzs);
            b[1] = (bf16_t)((float)((q >> 8) & 0xFFu) * scf - nzs);
            b[2] = (bf16_t)((float)((q >> 16) & 0xFFu)* scf - nzs);
            b[3] = (bf16_t)((float)(q >> 24)          * scf - nzs);
            *(bf16x4*)&Bls[bcol * LDSS + prel * 4] = b;
        }
        __syncthreads();
        #pragma unroll
        for (int ks = 0; ks < 2; ++ks) {
            bf16x8 af[4], bfv[4];
            #pragma unroll
            for (int t = 0; t < 4; ++t) {
                af[t]  = *(const bf16x8*)&Als[(wm + t * 16 + lr) * LDSS + ks * 32 + lq * 8];
                bfv[t] = *(const bf16x8*)&Bls[(wn + t * 16 + lr) * LDSS + ks * 32 + lq * 8];
            }
            #pragma unroll
            for (int i = 0; i < 4; ++i)
                #pragma unroll
                for (int j = 0; j < 4; ++j)
                    acc[i][j] = __builtin_amdgcn_mfma_f32_16x16x32_bf16(af[i], bfv[j], acc[i][j], 0, 0, 0);
        }
        __syncthreads();
    }
    #pragma unroll
    for (int j = 0; j < 4; ++j) {
        const int col = n0 + wn + j * 16 + lr;
        const float bv = bias[col];
        #pragma unroll
        for (int i = 0; i < 4; ++i) {
            const int rbs = m0 + wm + i * 16 + lq * 4;
            #pragma unroll
            for (int r = 0; r < 4; ++r)
                out[(size_t)(rbs + r) * OUTFEAT + col] = acc[i][j][r] + bv;
        }
    }
}

extern "C" void kernel_launch(void* const* d_in, const int* in_sizes, int n_in,
                              void* d_out, int out_size, void* d_ws, size_t ws_size,
                              hipStream_t stream) {
    const float*        x      = (const float*)d_in[0];
    const unsigned int* qw     = (const unsigned int*)d_in[1];
    const float*        scales = (const float*)d_in[2];
    const int*          zeros  = (const int*)d_in[3];
    const float*        bias   = (const float*)d_in[4];
    float*              out    = (float*)d_out;

    const size_t wt_bytes = (size_t)OUTFEAT * INFEAT;        // 45.1 MB i8 transposed weights
    const size_t xq_bytes = (size_t)TOKENS * INFEAT;         // 8.4 MB packed i8 x
    const size_t need = wt_bytes + xq_bytes + TOKENS * (sizeof(float) + sizeof(int)) + 256;

    if (ws_size >= need) {
        unsigned char* wt = (unsigned char*)d_ws;
        unsigned int* xq  = (unsigned int*)((char*)d_ws + wt_bytes);
        float* xscale = (float*)((char*)d_ws + wt_bytes + xq_bytes);
        int*   xsum   = (int*)((char*)d_ws + wt_bytes + xq_bytes + TOKENS * sizeof(float));

        prep<<<dim3(2752 + TOKENS), dim3(256), 0, stream>>>(x, qw, xq, xscale, xsum, wt);
        q3gemm_i8d<<<dim3((OUTFEAT / 128) * (TOKENS / 128)), dim3(256), 0, stream>>>(
            (const unsigned char*)xq, wt, scales, zeros, bias, xscale, xsum, out);
    } else {
        q3gemm_fb<<<dim3(OUTFEAT / 128, TOKENS / 128), dim3(256), 0, stream>>>(
            x, qw, scales, zeros, bias, out);
    }
}